// Round 13
// baseline (972.311 us; speedup 1.0000x reference)
//
#include <hip/hip_runtime.h>
#include <hip/hip_bf16.h>

#define Tn 1024
#define Bn 64
#define En 128
#define G4 512
#define NEGV -10000.0f

typedef _Float16 h8v __attribute__((ext_vector_type(8)));
typedef short bh8 __attribute__((ext_vector_type(8)));
typedef float fl4 __attribute__((ext_vector_type(4)));
typedef int i8v __attribute__((ext_vector_type(8)));

// ---------- bf16 helpers ----------
__device__ __forceinline__ float bf2f(unsigned short u) {
    unsigned int v = ((unsigned int)u) << 16;
    float f;
    __builtin_memcpy(&f, &v, 4);
    return f;
}
__device__ __forceinline__ unsigned short f2bf(float f) {
    unsigned int u;
    __builtin_memcpy(&u, &f, 4);
    u = (u + 0x7fffu + ((u >> 16) & 1u)) >> 16;
    return (unsigned short)u;
}

// ---------- fp8 e4m3fn encode ----------
__device__ __forceinline__ unsigned char f8enc(float x) {
#if __has_builtin(__builtin_amdgcn_cvt_pk_fp8_f32)
    int pk = __builtin_amdgcn_cvt_pk_fp8_f32(x, 0.0f, 0, false);
    return (unsigned char)(pk & 0xff);
#else
    unsigned u;
    __builtin_memcpy(&u, &x, 4);
    unsigned s = (u >> 31) << 7;
    float a = fabsf(x);
    if (!(a > 0.0f)) return (unsigned char)s;
    if (a >= 464.0f) return (unsigned char)(s | 0x7E);
    if (a < 0.015625f) {
        int q = (int)rintf(a * 512.0f);
        return (unsigned char)(s | (unsigned)q);
    }
    int ex;
    (void)frexpf(a, &ex);
    int E = ex - 1;
    float t = ldexpf(a, -E);
    int m3 = (int)rintf((t - 1.0f) * 8.0f);
    if (m3 == 8) { m3 = 0; E += 1; }
    if (E > 8) return (unsigned char)(s | 0x7E);
    return (unsigned char)(s | ((unsigned)(E + 7) << 3) | (unsigned)m3);
#endif
}

__device__ __forceinline__ float sigf(float x) { return 1.0f / (1.0f + __expf(-x)); }
__device__ __forceinline__ float tanhfast(float x) { return 1.0f - 2.0f / (1.0f + __expf(2.0f * x)); }

// lgkm-only barrier: LDS visibility without draining vmcnt.
__device__ __forceinline__ void barrier_lds_only() {
    __builtin_amdgcn_s_waitcnt(0xC07F);
    __builtin_amdgcn_s_barrier();
}

// =====================================================================
// K0: one-time weight conversion whh (fp32, both dirs) -> fp8 e4m3 x64.
// =====================================================================
__global__ __launch_bounds__(256) void k_wcvt(
    const float* __restrict__ wf, const float* __restrict__ wb,
    unsigned char* __restrict__ o)
{
    const int i = blockIdx.x * 256 + threadIdx.x;   // 0 .. 131071
    const float v = (i < 65536) ? wf[i] : wb[i - 65536];
    o[i] = f8enc(v * 64.0f);
}

// =====================================================================
// K1: input projection via bf16 MFMA, nt-MERGED (the R13 fix):
// stage the embed-gather A tile ONCE, loop the 4 B tiles (w_ih n-slices)
// against it. Gather traffic 268 MB -> 67 MB; A staging VALU / 4.
// Grid (512, 1, 2), 256 threads.
// =====================================================================
__global__ __launch_bounds__(256) void k_inproj(
    const int* __restrict__ sent, const float* __restrict__ embed,
    const float* __restrict__ w_ih_f, const float* __restrict__ b_ih_f, const float* __restrict__ b_hh_f,
    const float* __restrict__ w_ih_b, const float* __restrict__ b_ih_b, const float* __restrict__ b_hh_b,
    unsigned short* __restrict__ G_f, unsigned short* __restrict__ G_b)
{
    __shared__ unsigned short Asm[128][136];
    __shared__ unsigned short Bsm[128][136];
    const int tid = threadIdx.x;
    const int dir = blockIdx.z;
    const float* w_ih = dir ? w_ih_b : w_ih_f;
    const float* bi   = dir ? b_ih_b : b_ih_f;
    const float* bh   = dir ? b_hh_b : b_hh_f;
    unsigned short* Gout = dir ? G_b : G_f;

    const int mt = blockIdx.x;
    const int r0 = mt * 128;

    const int srow = tid >> 1;
    const int ch = (tid & 1) * 64;

    // ---- stage A (embed gather) ONCE ----
    {
        const int rg = r0 + srow;
        const int tt = rg >> 6, bb = rg & 63;
        const int tok = sent[bb * Tn + tt];
        const float* ar = embed + (size_t)tok * En + ch;
#pragma unroll
        for (int i = 0; i < 64; i += 4) {
            float4 v = *(const float4*)(ar + i);
            *(unsigned*)&Asm[srow][ch + i]     = (unsigned)f2bf(v.x) | ((unsigned)f2bf(v.y) << 16);
            *(unsigned*)&Asm[srow][ch + i + 2] = (unsigned)f2bf(v.z) | ((unsigned)f2bf(v.w) << 16);
        }
    }

    const int w = tid >> 6, lane = tid & 63;
    const int ln = lane & 15, lq = lane >> 4;
    const int nwb = w * 32;

    for (int nt = 0; nt < 4; ++nt) {
        const int n0 = nt * 128;
        if (nt) __syncthreads();      // protect Bsm overwrite vs prior MFMA reads

        // ---- stage B tile (w_ih rows n0..n0+127; 256 KB table, L2-hot) ----
        {
            const float* br = w_ih + (size_t)(n0 + srow) * En + ch;
#pragma unroll
            for (int i = 0; i < 64; i += 4) {
                float4 u = *(const float4*)(br + i);
                *(unsigned*)&Bsm[srow][ch + i]     = (unsigned)f2bf(u.x) | ((unsigned)f2bf(u.y) << 16);
                *(unsigned*)&Bsm[srow][ch + i + 2] = (unsigned)f2bf(u.z) | ((unsigned)f2bf(u.w) << 16);
            }
        }
        __syncthreads();              // A (first iter) + B visible

        fl4 acc[8][2];
#pragma unroll
        for (int mi = 0; mi < 8; ++mi)
#pragma unroll
            for (int ni = 0; ni < 2; ++ni) acc[mi][ni] = (fl4){0.f, 0.f, 0.f, 0.f};

#pragma unroll
        for (int kt = 0; kt < 4; ++kt) {
            const int kc = kt * 32 + lq * 8;
            bh8 a[8], bf[2];
#pragma unroll
            for (int mi = 0; mi < 8; ++mi) a[mi] = *(const bh8*)&Asm[mi * 16 + ln][kc];
#pragma unroll
            for (int ni = 0; ni < 2; ++ni) bf[ni] = *(const bh8*)&Bsm[nwb + ni * 16 + ln][kc];
#pragma unroll
            for (int mi = 0; mi < 8; ++mi)
#pragma unroll
                for (int ni = 0; ni < 2; ++ni)
                    acc[mi][ni] = __builtin_amdgcn_mfma_f32_16x16x32_bf16(a[mi], bf[ni], acc[mi][ni], 0, 0, 0);
        }

        float bias[2];
#pragma unroll
        for (int ni = 0; ni < 2; ++ni) {
            int n = n0 + nwb + ni * 16 + ln;
            bias[ni] = bi[n] + bh[n];
        }
#pragma unroll
        for (int mi = 0; mi < 8; ++mi)
#pragma unroll
            for (int ni = 0; ni < 2; ++ni) {
                const int n = n0 + nwb + ni * 16 + ln;
#pragma unroll
                for (int rg = 0; rg < 4; ++rg) {
                    const int m = mi * 16 + lq * 4 + rg;
                    const size_t r = (size_t)(r0 + m);
                    Gout[(r << 9) + n] = f2bf(acc[mi][ni][rg] + bias[ni]);
                }
            }
    }
}

// =====================================================================
// K2: LSTM recurrence with K=128 fp8 MFMA (UNCHANGED from R12 - 589 us).
// =====================================================================
__global__ __launch_bounds__(512, 2) void k_lstm(
    const unsigned char* __restrict__ whh8,
    const unsigned short* __restrict__ G_f, const unsigned short* __restrict__ G_b,
    unsigned short* __restrict__ h_f, unsigned short* __restrict__ h_b)
{
    const int tid = threadIdx.x;
    const int w = tid >> 6;
    const int lane = tid & 63;
    const int ln = lane & 15;
    const int quad = lane >> 4;
    const int b = blockIdx.x;
    const int dir = blockIdx.y;
    const unsigned short* Gd = dir ? G_b : G_f;
    unsigned short* ho = dir ? h_b : h_f;

    const int j = w * 16 + ln;

    __shared__ __align__(16) unsigned char hls8[2][128];

    const unsigned char* wb8 = whh8 + (size_t)dir * 65536;
    const i8v w0 = *(const i8v*)(wb8 + ((size_t)(0 * 128 + j) << 7) + quad * 32);
    const i8v w1 = *(const i8v*)(wb8 + ((size_t)(1 * 128 + j) << 7) + quad * 32);
    const i8v w2 = *(const i8v*)(wb8 + ((size_t)(2 * 128 + j) << 7) + quad * 32);
    const i8v w3 = *(const i8v*)(wb8 + ((size_t)(3 * 128 + j) << 7) + quad * 32);

    if (tid < 64) ((unsigned*)hls8)[tid] = 0u;
    float c = 0.0f;
    __syncthreads();

    unsigned short gp[4][4];
#pragma unroll
    for (int u = 0; u < 4; ++u) {
        const int tt = dir ? (Tn - 1 - u) : u;
        const unsigned short* gpp = Gd + (((size_t)tt * Bn + b) << 9) + j;
#pragma unroll
        for (int q = 0; q < 4; ++q) gp[u][q] = gpp[q * 128];
    }

    const float ds = 0.0009765625f;     // 1/(64*16) descale

    for (int blk = 0; blk < Tn / 4; ++blk) {
#pragma unroll
        for (int u = 0; u < 4; ++u) {
            const int s = blk * 4 + u;
            const int t = dir ? (Tn - 1 - s) : s;
            const int p = u & 1;

            const unsigned short ga0 = gp[u][0], ga1 = gp[u][1];
            const unsigned short ga2 = gp[u][2], ga3 = gp[u][3];

            if (s + 4 < Tn) {
                const int tt = dir ? (Tn - 1 - (s + 4)) : (s + 4);
                const unsigned short* gpp = Gd + (((size_t)tt * Bn + b) << 9) + j;
#pragma unroll
                for (int q = 0; q < 4; ++q) gp[u][q] = gpp[q * 128];
            }

            i8v ha = *(const i8v*)&hls8[p][quad * 32];

            const fl4 z = (fl4){0.f, 0.f, 0.f, 0.f};
            fl4 a0 = __builtin_amdgcn_mfma_scale_f32_16x16x128_f8f6f4(
                         ha, w0, z, 0, 0, 0, 0x7F7F7F7F, 0, 0x7F7F7F7F);
            fl4 a1 = __builtin_amdgcn_mfma_scale_f32_16x16x128_f8f6f4(
                         ha, w1, z, 0, 0, 0, 0x7F7F7F7F, 0, 0x7F7F7F7F);
            fl4 a2 = __builtin_amdgcn_mfma_scale_f32_16x16x128_f8f6f4(
                         ha, w2, z, 0, 0, 0, 0x7F7F7F7F, 0, 0x7F7F7F7F);
            fl4 a3 = __builtin_amdgcn_mfma_scale_f32_16x16x128_f8f6f4(
                         ha, w3, z, 0, 0, 0, 0x7F7F7F7F, 0, 0x7F7F7F7F);

            float pi = a0[0] * ds + bf2f(ga0);
            float pf = a1[0] * ds + bf2f(ga1);
            float pg = a2[0] * ds + bf2f(ga2);
            float po = a3[0] * ds + bf2f(ga3);
            float iv = sigf(pi), fv = sigf(pf), gv = tanhfast(pg), ov = sigf(po);
            c = fv * c + iv * gv;
            float hn = ov * tanhfast(c);

            if (quad == 0) {
                hls8[1 - p][j] = f8enc(hn * 16.0f);
                ho[(((size_t)t * Bn + b) << 7) + j] = f2bf(hn);
            }

            barrier_lds_only();
        }
    }
}

// =====================================================================
// K3: feats (unchanged).
// =====================================================================
__global__ __launch_bounds__(256) void k_feats(
    const unsigned short* __restrict__ h_f, const unsigned short* __restrict__ h_b,
    const float* __restrict__ w_out, const float* __restrict__ b_out,
    float* __restrict__ feats)
{
    __shared__ float wl[256][12];
    __shared__ float bl[12];
    const int tid = threadIdx.x;
#pragma unroll
    for (int s = 0; s < 9; ++s) wl[tid][s] = w_out[s * 256 + tid];
#pragma unroll
    for (int s = 9; s < 12; ++s) wl[tid][s] = 0.0f;
    if (tid < 12) bl[tid] = (tid < 9) ? b_out[tid] : 0.0f;
    __syncthreads();

    const int r = blockIdx.x * 256 + tid;
    const unsigned short* hfr = h_f + (size_t)r * 128;
    const unsigned short* hbr = h_b + (size_t)r * 128;
    float acc[12];
#pragma unroll
    for (int k = 0; k < 12; ++k) acc[k] = bl[k];

    for (int ch = 0; ch < 32; ++ch) {
        const unsigned short* src = (ch < 16) ? (hfr + ch * 8) : (hbr + (ch - 16) * 8);
        uint4 hv = *(const uint4*)src;
        unsigned int hw0 = hv.x, hw1 = hv.y, hw2 = hv.z, hw3 = hv.w;
        const int jb = ch * 8;
#pragma unroll
        for (int q = 0; q < 8; ++q) {
            unsigned int word = (q < 2) ? hw0 : ((q < 4) ? hw1 : ((q < 6) ? hw2 : hw3));
            unsigned short hs = (q & 1) ? (unsigned short)(word >> 16) : (unsigned short)(word & 0xffff);
            float hf = bf2f(hs);
            const float* wrp = &wl[jb + q][0];
            float4 w0 = *(const float4*)(wrp);
            float4 w1 = *(const float4*)(wrp + 4);
            float4 w2 = *(const float4*)(wrp + 8);
            acc[0] += hf * w0.x; acc[1] += hf * w0.y; acc[2] += hf * w0.z; acc[3] += hf * w0.w;
            acc[4] += hf * w1.x; acc[5] += hf * w1.y; acc[6] += hf * w1.z; acc[7] += hf * w1.w;
            acc[8] += hf * w2.x; acc[9] += hf * w2.y; acc[10] += hf * w2.z; acc[11] += hf * w2.w;
        }
    }
    float* fr = feats + (size_t)r * 9;
#pragma unroll
    for (int k = 0; k < 9; ++k) fr[k] = acc[k];
}

// =====================================================================
// K4: Viterbi, register-DP (the R13 fix): delta lives in a register per
// lane (lane tag = tid<9); per-step broadcast via 9 pipelined __shfl
// instead of the dependent LDS write->b128-read round-trip (~180 cyc/iter).
// All 64 lanes run the loop (shfl needs active sources); stores guarded.
// =====================================================================
__global__ __launch_bounds__(64) void k_viterbi(
    const float* __restrict__ feats, const float* __restrict__ trans,
    float* __restrict__ out)
{
    __shared__ __align__(16) unsigned char bp[1024 * 16];   // 16 KB
    __shared__ float fl[1024 * 9];                          // 36 KB
    __shared__ unsigned char pt[1024];

    const int b = blockIdx.x, tid = threadIdx.x;

    for (int i = tid; i < 9216; i += 64) {
        int t = i / 9;
        int n = i - t * 9;
        fl[i] = feats[((size_t)t * 64 + b) * 9 + n];
    }

    const int ct = (tid < 9) ? tid : 0;     // clamped tag for safe loads
    const float tr0 = trans[ct * 9 + 0], tr1 = trans[ct * 9 + 1], tr2 = trans[ct * 9 + 2];
    const float tr3 = trans[ct * 9 + 3], tr4 = trans[ct * 9 + 4], tr5 = trans[ct * 9 + 5];
    const float tr6 = trans[ct * 9 + 6], tr7 = trans[ct * 9 + 7], tr8 = trans[ct * 9 + 8];
    const float trs = trans[8 * 9 + ct];
    float d = (tid == 7) ? 0.0f : NEGV;     // START = 7
    __syncthreads();

    for (int t = 0; t < 1024; ++t) {
        // broadcast all 9 deltas (9 independent bpermutes, pipelined)
        float d0 = __shfl(d, 0, 64), d1 = __shfl(d, 1, 64), d2 = __shfl(d, 2, 64);
        float d3 = __shfl(d, 3, 64), d4 = __shfl(d, 4, 64), d5 = __shfl(d, 5, 64);
        float d6 = __shfl(d, 6, 64), d7 = __shfl(d, 7, 64), d8 = __shfl(d, 8, 64);
        float m = d0 + tr0; int am = 0;
        float v;
        v = d1 + tr1; if (v > m) { m = v; am = 1; }
        v = d2 + tr2; if (v > m) { m = v; am = 2; }
        v = d3 + tr3; if (v > m) { m = v; am = 3; }
        v = d4 + tr4; if (v > m) { m = v; am = 4; }
        v = d5 + tr5; if (v > m) { m = v; am = 5; }
        v = d6 + tr6; if (v > m) { m = v; am = 6; }
        v = d7 + tr7; if (v > m) { m = v; am = 7; }
        v = d8 + tr8; if (v > m) { m = v; am = 8; }
        d = m + fl[t * 9 + ct];
        if (tid < 9) bp[t * 16 + tid] = (unsigned char)am;
    }
    __syncthreads();

    // terminal: tv = delta[n] + trans[STOP][n]
    float tv = (tid < 9) ? (d + trs) : -3.0e38f;
    int bi = tid;
#pragma unroll
    for (int off = 8; off >= 1; off >>= 1) {
        float ov = __shfl_down(tv, off, 64);
        int oi = __shfl_down(bi, off, 64);
        if (ov > tv || (ov == tv && oi < bi)) { tv = ov; bi = oi; }
    }
    int best = __shfl(bi, 0, 64);
    if (tid == 0) out[b] = tv;

    if (tid == 0) {
        int tag = best;
        for (int t0 = 1023; t0 >= 0; t0 -= 8) {
            uint4 rows[8];
#pragma unroll
            for (int i = 0; i < 8; ++i) rows[i] = *(const uint4*)&bp[(t0 - i) * 16];
#pragma unroll
            for (int i = 0; i < 8; ++i) {
                pt[t0 - i] = (unsigned char)tag;
                uint4 rw = rows[i];
                unsigned int sel = (unsigned int)tag >> 2;
                unsigned int word = (sel == 0) ? rw.x : ((sel == 1) ? rw.y : rw.z);
                tag = (int)((word >> ((tag & 3) * 8)) & 0xffu);
            }
        }
    }
    __syncthreads();
    for (int i = tid; i < 1024; i += 64) {
        out[64 + b * 1024 + i] = (float)pt[i];
    }
}

// =====================================================================
extern "C" void kernel_launch(void* const* d_in, const int* in_sizes, int n_in,
                              void* d_out, int out_size, void* d_ws, size_t ws_size,
                              hipStream_t stream) {
    const int*   sent   = (const int*)d_in[0];
    const float* embed  = (const float*)d_in[1];
    const float* w_ih_f = (const float*)d_in[2];
    const float* w_hh_f = (const float*)d_in[3];
    const float* b_ih_f = (const float*)d_in[4];
    const float* b_hh_f = (const float*)d_in[5];
    const float* w_ih_b = (const float*)d_in[6];
    const float* w_hh_b = (const float*)d_in[7];
    const float* b_ih_b = (const float*)d_in[8];
    const float* b_hh_b = (const float*)d_in[9];
    const float* w_out  = (const float*)d_in[10];
    const float* b_out  = (const float*)d_in[11];
    const float* trans  = (const float*)d_in[12];
    float* out = (float*)d_out;

    unsigned short* G_f = (unsigned short*)d_ws;
    unsigned short* G_b = G_f + (size_t)Tn * Bn * G4;
    unsigned short* h_f = G_b + (size_t)Tn * Bn * G4;
    unsigned short* h_b = h_f + (size_t)Tn * Bn * 128;
    float* feats = (float*)(h_b + (size_t)Tn * Bn * 128);
    unsigned char* whh8 = (unsigned char*)(feats + (size_t)Tn * Bn * 9);

    k_wcvt<<<512, 256, 0, stream>>>(w_hh_f, w_hh_b, whh8);
    k_inproj<<<dim3(512, 1, 2), 256, 0, stream>>>(sent, embed,
        w_ih_f, b_ih_f, b_hh_f, w_ih_b, b_ih_b, b_hh_b, G_f, G_b);
    k_lstm<<<dim3(64, 2), 512, 0, stream>>>(whh8, G_f, G_b, h_f, h_b);
    k_feats<<<256, 256, 0, stream>>>(h_f, h_b, w_out, b_out, feats);
    k_viterbi<<<64, 64, 0, stream>>>(feats, trans, out);
}